// Round 3
// baseline (230.053 us; speedup 1.0000x reference)
//
#include <hip/hip_runtime.h>
#include <math.h>

#define S_LEN 2048
#define NHEAD 16
#define HDIM  64

typedef __attribute__((ext_vector_type(8))) short bf16x8;
typedef __attribute__((ext_vector_type(4))) float f32x4;

__device__ __forceinline__ unsigned short f2bf(float f) {
    union { float f; unsigned u; } v; v.f = f;
    unsigned r = v.u + 0x7fffu + ((v.u >> 16) & 1u);
    return (unsigned short)(r >> 16);
}

// async 16B global->LDS. LDS dest must be wave-uniform base + lane*16.
__device__ __forceinline__ void gl2lds16(const void* g, void* l) {
    __builtin_amdgcn_global_load_lds(
        (__attribute__((address_space(1))) void*)(void*)(g),
        (__attribute__((address_space(3))) void*)(l), 16, 0, 0);
}

// =====================================================================
// Kernel 0: fused fp32->bf16 convert (blocks 0..8191) + RoPE table build
// (blocks 8192..8447). dst: hs[4M] | Wq[1M] | Wk[1M] | Wv[1M] | Wo[1M]
// =====================================================================
__global__ __launch_bounds__(256) void convert_kernel(
    const float* __restrict__ hs, const float* __restrict__ Wq,
    const float* __restrict__ Wk, const float* __restrict__ Wv,
    const float* __restrict__ Wo, unsigned short* __restrict__ dst,
    float2* __restrict__ rtab)
{
    const int bid = blockIdx.x;
    if (bid >= 8192) {
        const int gid = (bid - 8192) * 256 + threadIdx.x;   // 65536
        const int s = gid >> 5, i = gid & 31;
        const float l2c = 0.41524101186092029f;             // log2(10000)/32
        const float freq = exp2f(-(float)i * l2c);
        const float ang = (float)s * freq;
        float2 cs;
        cs.x = cosf(ang);
        cs.y = sinf(ang);
        rtab[gid] = cs;
        return;
    }
    const int gid = bid * 256 + threadIdx.x;
    const int n = gid << 2;
    const float* src; int off;
    if (n < (4 << 20))      { src = hs; off = n; }
    else if (n < (5 << 20)) { src = Wq; off = n - (4 << 20); }
    else if (n < (6 << 20)) { src = Wk; off = n - (5 << 20); }
    else if (n < (7 << 20)) { src = Wv; off = n - (6 << 20); }
    else                    { src = Wo; off = n - (7 << 20); }
    const float4 v = *(const float4*)(src + off);
    ushort4 o;
    o.x = f2bf(v.x); o.y = f2bf(v.y); o.z = f2bf(v.z); o.w = f2bf(v.w);
    *(ushort4*)(dst + n) = o;
}

// =====================================================================
// Kernel 1: QKV GEMM, bf16 MFMA 16x16x32, tile 128x128 BK=64, RoPE fused.
// B-rows staged PERMUTED (tau) so each lane's 4 output columns pack:
//   Q/K: tau(r) = 2*ln + (jt&1) + 32*(jt>>1)  -> lane holds {n,n+1,n+32,n+33}
//        RoPE pairs in-lane, 1 float4 rtab load, 2x b32 stores
//   V:   tau(r) = 4*ln + jt                   -> 1x b64 store, float4 bias
// Output layouts stay IDENTITY -> zero downstream changes.
// =====================================================================
__global__ __launch_bounds__(256, 3) void qkv_gemm_kernel(
    const unsigned short* __restrict__ X,     // [4096][1024] bf16
    const unsigned short* __restrict__ Wall,  // wq|wk|wv (1M each)
    const float* __restrict__ bq, const float* __restrict__ bk,
    const float* __restrict__ bv, const float2* __restrict__ rtab,
    unsigned short* __restrict__ qo, unsigned short* __restrict__ ko,
    unsigned short* __restrict__ vo)
{
    __shared__ unsigned short As[128 * 64];
    __shared__ unsigned short Bs[128 * 64];

    const int mat = blockIdx.x >> 3;
    const int n0  = (blockIdx.x & 7) << 7;
    const int m0  = blockIdx.y << 7;
    const unsigned short* W = Wall + (mat << 20);
    const float* bias = (mat == 0) ? bq : (mat == 1) ? bk : bv;
    unsigned short* out = (mat == 0) ? qo : (mat == 1) ? ko : vo;

    const int tid = threadIdx.x;
    const int wave = tid >> 6, lane = tid & 63;
    const int quad = lane >> 4, ln = lane & 15;
    const int wm = (wave >> 1) << 6, wn = (wave & 1) << 6;

    // hoisted staging pointers (tau row-permutation on B)
    const unsigned short* xptr[4];
    const unsigned short* wptr[4];
    #pragma unroll
    for (int L = 0; L < 4; ++L) {
        const int i = tid + (L << 8);
        const int r = i >> 3, cl = i & 7;
        const int cg = (cl ^ (r & 7)) << 3;
        const int rq = r & 63;
        const int tau = (mat < 2)
            ? ((r & 64) | ((rq & 15) << 1) | ((rq >> 4) & 1) | (((rq >> 5) & 1) << 5))
            : ((r & 64) | ((rq & 15) << 2) | (rq >> 4));
        xptr[L] = X + (m0 + r) * 1024 + cg;
        wptr[L] = W + (n0 + tau) * 1024 + cg;
    }

    f32x4 acc[4][4] = {};

    for (int k0 = 0; k0 < 1024; k0 += 64) {
        #pragma unroll
        for (int L = 0; L < 4; ++L) {
            const int i = tid + (L << 8);
            gl2lds16(xptr[L] + k0, &As[i << 3]);
            gl2lds16(wptr[L] + k0, &Bs[i << 3]);
        }
        __syncthreads();
        #pragma unroll
        for (int s = 0; s < 2; ++s) {
            bf16x8 a[4], b[4];
            #pragma unroll
            for (int t = 0; t < 4; ++t) {
                const int ra = wm + (t << 4) + ln;
                a[t] = *(const bf16x8*)&As[(ra << 6) + ((((s << 2) | quad) ^ (ra & 7)) << 3)];
                const int rb = wn + (t << 4) + ln;
                b[t] = *(const bf16x8*)&Bs[(rb << 6) + ((((s << 2) | quad) ^ (rb & 7)) << 3)];
            }
            #pragma unroll
            for (int i = 0; i < 4; ++i)
                #pragma unroll
                for (int j = 0; j < 4; ++j)
                    acc[i][j] = __builtin_amdgcn_mfma_f32_16x16x32_bf16(a[i], b[j], acc[i][j], 0, 0, 0);
        }
        __syncthreads();
    }

    const int h = (n0 + wn) >> 6;

    if (mat < 2) {
        const int nb = n0 + wn + (ln << 1);
        const float b0 = bias[nb],      b1 = bias[nb + 1];
        const float b2 = bias[nb + 32], b3 = bias[nb + 33];
        #pragma unroll
        for (int i = 0; i < 4; ++i) {
            #pragma unroll
            for (int reg = 0; reg < 4; ++reg) {
                const int m = m0 + wm + (i << 4) + (quad << 2) + reg;
                const int b_ = m >> 11, s_ = m & 2047;
                unsigned short* o = out + ((((b_ << 4) + h) << 11) + s_) * 64;
                const float4 cs = *(const float4*)(rtab + (s_ << 5) + (ln << 1));
                const float x1a = acc[i][0][reg] + b0, x1b = acc[i][1][reg] + b1;
                const float x2a = acc[i][2][reg] + b2, x2b = acc[i][3][reg] + b3;
                const float r0a = x1a * cs.x - x2a * cs.y;
                const float r0b = x1b * cs.z - x2b * cs.w;
                const float r1a = x2a * cs.x + x1a * cs.y;
                const float r1b = x2b * cs.z + x1b * cs.w;
                const unsigned ua = __float_as_uint(r0a) + 0x8000u;
                const unsigned ub = __float_as_uint(r0b) + 0x8000u;
                const unsigned uc = __float_as_uint(r1a) + 0x8000u;
                const unsigned ud = __float_as_uint(r1b) + 0x8000u;
                *(unsigned*)(o + (ln << 1))      = __builtin_amdgcn_perm(ub, ua, 0x07060302u);
                *(unsigned*)(o + 32 + (ln << 1)) = __builtin_amdgcn_perm(ud, uc, 0x07060302u);
            }
        }
    } else {
        const float4 bv4 = *(const float4*)(bias + n0 + wn + (ln << 2));
        #pragma unroll
        for (int i = 0; i < 4; ++i)
            #pragma unroll
            for (int reg = 0; reg < 4; ++reg) {
                const int m = m0 + wm + (i << 4) + (quad << 2) + reg;
                const int b_ = m >> 11, s_ = m & 2047;
                unsigned short* o = out + ((((b_ << 4) + h) << 11) + s_) * 64;
                const unsigned ua = __float_as_uint(acc[i][0][reg] + bv4.x) + 0x8000u;
                const unsigned ub = __float_as_uint(acc[i][1][reg] + bv4.y) + 0x8000u;
                const unsigned uc = __float_as_uint(acc[i][2][reg] + bv4.z) + 0x8000u;
                const unsigned ud = __float_as_uint(acc[i][3][reg] + bv4.w) + 0x8000u;
                uint2 w;
                w.x = __builtin_amdgcn_perm(ub, ua, 0x07060302u);
                w.y = __builtin_amdgcn_perm(ud, uc, 0x07060302u);
                *(uint2*)(o + (ln << 2)) = w;
            }
    }
}

// =====================================================================
// Kernel 2: V transpose [B,H,S,HD] -> [B,H,HD,S] (identity layouts).
// =====================================================================
__global__ __launch_bounds__(256) void vtrans_kernel(
    const unsigned short* __restrict__ v, unsigned short* __restrict__ vt)
{
    __shared__ unsigned short T[64][66];
    const int bh = blockIdx.x >> 5;
    const int s0 = (blockIdx.x & 31) << 6;
    const int tid = threadIdx.x;
    #pragma unroll
    for (int L = 0; L < 4; ++L) {
        const int i = tid + (L << 8);
        const int r = i >> 4, c4 = (i & 15) << 2;
        const ushort4 in = *(const ushort4*)(v + ((bh << 11) + s0 + r) * 64 + c4);
        T[r][c4 + 0] = in.x; T[r][c4 + 1] = in.y;
        T[r][c4 + 2] = in.z; T[r][c4 + 3] = in.w;
    }
    __syncthreads();
    #pragma unroll
    for (int L = 0; L < 4; ++L) {
        const int i = tid + (L << 8);
        const int hd = i >> 4, c4 = (i & 15) << 2;
        ushort4 o;
        o.x = T[c4 + 0][hd]; o.y = T[c4 + 1][hd];
        o.z = T[c4 + 2][hd]; o.w = T[c4 + 3][hd];
        *(ushort4*)(vt + ((bh << 6) + hd) * 2048 + s0 + c4) = o;
    }
}

// =====================================================================
// Kernel 3: flash v8 — 8 waves / 128 q-rows, kt loop UNROLLED x2 with
// compile-time buffer index. All swizzled LDS offsets hoisted to regs
// (K/V frag x8, P-write x4, P-read x2; s=1 variant = s=0 ^ 32).
// mA/mB mask ping-pong (no mcur<-mnext copies). Running global staging
// pointers. s_setprio(1) around MFMA clusters (T5).
// R2 post-mortem: VALUBusy 40% implied ~300 VALU ops/thread/kt vs ~100
// necessary -> per-kt address recompute + mask copies were the overhead.
// Buffer protocol identical to v7: prologue stages kt0->buf0; halfA
// stages 2it+1->buf1, computes buf0; halfB stages 2it+2->buf0 (it<15),
// computes buf1. One barrier per half.
// =====================================================================
__global__ __launch_bounds__(512, 4) void flash_kernel(
    const unsigned short* __restrict__ qb, const unsigned short* __restrict__ kb,
    const unsigned short* __restrict__ vtb, const float* __restrict__ mask,
    unsigned short* __restrict__ attn)
{
    __shared__ unsigned short Ks[2][64 * 64];
    __shared__ unsigned short Vt[2][64 * 64];
    __shared__ unsigned short Ps[8 * 1024];

    const int qt = blockIdx.x & 15;
    const int bh = blockIdx.x >> 4;
    const int b_ = bh >> 4, h = bh & 15;
    const int q0 = qt << 7;

    const int tid = threadIdx.x;
    const int wave = tid >> 6, lane = tid & 63;
    const int quad = lane >> 4, ln = lane & 15;

    const unsigned short* qrow = qb + ((size_t)((bh << 11) + q0 + (wave << 4) + ln) << 6);
    bf16x8 qa0 = *(const bf16x8*)(qrow + (quad << 3));
    bf16x8 qa1 = *(const bf16x8*)(qrow + 32 + (quad << 3));

    const float scale = 0.125f / logf(2048.0f);

    unsigned short* Pw = Ps + (wave << 10);

    // ---- hoisted swizzled LDS offsets (loop-invariant) ----
    int kvo0[4], kvo1[4];
    #pragma unroll
    for (int j = 0; j < 4; ++j) {
        const int r = (j << 4) + ln;
        kvo0[j] = (r << 6) + ((quad ^ (r & 7)) << 3);
        kvo1[j] = kvo0[j] ^ 32;
    }
    int po[4];
    #pragma unroll
    for (int reg = 0; reg < 4; ++reg) {
        const int pr = (quad << 2) + reg;
        po[reg] = (pr << 6) + (((ln >> 1) ^ (pr & 7)) << 3) + ((ln & 1) << 2);
    }
    const int pro0 = (ln << 6) + ((quad ^ (ln & 7)) << 3);
    const int pro1 = pro0 ^ 32;

    // ---- running global pointers ----
    const int r0 = tid >> 3, c0 = ((tid & 7) ^ (r0 & 7)) << 3;
    const int p0 = ((r0 & 15) << 2) + (r0 >> 4);
    const unsigned short* kg = kb + ((bh << 11) + p0) * 64 + c0;
    const unsigned short* vg = vtb + ((bh << 6) + r0) * 2048 + c0;
    const float* mptr = mask + ((size_t)b_ << 22)
                      + ((size_t)(q0 + (wave << 4) + (quad << 2)) << 11) + (ln << 2);

    float l_i[4] = {0.f, 0.f, 0.f, 0.f};
    f32x4 O[4] = {};

    // prologue: stage kt0 -> buf0, load mask kt0 -> mA
    gl2lds16(kg, &Ks[0][tid << 3]);
    gl2lds16(vg, &Vt[0][tid << 3]);
    kg += 4096; vg += 64;
    float4 mA[4], mB[4];
    #pragma unroll
    for (int reg = 0; reg < 4; ++reg)
        mA[reg] = *(const float4*)(mptr + (reg << 11));
    mptr += 64;

#define FLASH_STEP(BUF, MR)                                                   \
    {                                                                         \
        f32x4 sacc[4] = {};                                                   \
        {                                                                     \
            bf16x8 bfr[4];                                                    \
            _Pragma("unroll")                                                 \
            for (int j = 0; j < 4; ++j)                                       \
                bfr[j] = *(const bf16x8*)&Ks[BUF][kvo0[j]];                   \
            __builtin_amdgcn_s_setprio(1);                                    \
            _Pragma("unroll")                                                 \
            for (int j = 0; j < 4; ++j)                                       \
                sacc[j] = __builtin_amdgcn_mfma_f32_16x16x32_bf16(            \
                    qa0, bfr[j], sacc[j], 0, 0, 0);                           \
            __builtin_amdgcn_s_setprio(0);                                    \
            _Pragma("unroll")                                                 \
            for (int j = 0; j < 4; ++j)                                       \
                bfr[j] = *(const bf16x8*)&Ks[BUF][kvo1[j]];                   \
            __builtin_amdgcn_s_setprio(1);                                    \
            _Pragma("unroll")                                                 \
            for (int j = 0; j < 4; ++j)                                       \
                sacc[j] = __builtin_amdgcn_mfma_f32_16x16x32_bf16(            \
                    qa1, bfr[j], sacc[j], 0, 0, 0);                           \
            __builtin_amdgcn_s_setprio(0);                                    \
        }                                                                     \
        _Pragma("unroll")                                                     \
        for (int reg = 0; reg < 4; ++reg) {                                   \
            float p0_ = __expf(fmaf(sacc[0][reg], scale, MR[reg].x));         \
            float p1_ = __expf(fmaf(sacc[1][reg], scale, MR[reg].y));         \
            float p2_ = __expf(fmaf(sacc[2][reg], scale, MR[reg].z));         \
            float p3_ = __expf(fmaf(sacc[3][reg], scale, MR[reg].w));         \
            l_i[reg] += (p0_ + p1_) + (p2_ + p3_);                            \
            unsigned u0 = __float_as_uint(p0_) + 0x8000u;                     \
            unsigned u1 = __float_as_uint(p1_) + 0x8000u;                     \
            unsigned u2 = __float_as_uint(p2_) + 0x8000u;                     \
            unsigned u3 = __float_as_uint(p3_) + 0x8000u;                     \
            uint2 w;                                                          \
            w.x = __builtin_amdgcn_perm(u1, u0, 0x07060302u);                 \
            w.y = __builtin_amdgcn_perm(u3, u2, 0x07060302u);                 \
            *(uint2*)&Pw[po[reg]] = w;                                        \
        }                                                                     \
        {                                                                     \
            bf16x8 a_ = *(const bf16x8*)&Pw[pro0];                            \
            bf16x8 bfr[4];                                                    \
            _Pragma("unroll")                                                 \
            for (int j = 0; j < 4; ++j)                                       \
                bfr[j] = *(const bf16x8*)&Vt[BUF][kvo0[j]];                   \
            __builtin_amdgcn_s_setprio(1);                                    \
            _Pragma("unroll")                                                 \
            for (int j = 0; j < 4; ++j)                                       \
                O[j] = __builtin_amdgcn_mfma_f32_16x16x32_bf16(               \
                    a_, bfr[j], O[j], 0, 0, 0);                               \
            __builtin_amdgcn_s_setprio(0);                                    \
            a_ = *(const bf16x8*)&Pw[pro1];                                   \
            _Pragma("unroll")                                                 \
            for (int j = 0; j < 4; ++j)                                       \
                bfr[j] = *(const bf16x8*)&Vt[BUF][kvo1[j]];                   \
            __builtin_amdgcn_s_setprio(1);                                    \
            _Pragma("unroll")                                                 \
            for (int j = 0; j < 4; ++j)                                       \
                O[j] = __builtin_amdgcn_mfma_f32_16x16x32_bf16(               \
                    a_, bfr[j], O[j], 0, 0, 0);                               \
            __builtin_amdgcn_s_setprio(0);                                    \
        }                                                                     \
    }

    for (int it = 0; it < 16; ++it) {
        // ---- half A: compute kt=2it (buf0, mA); stage kt=2it+1 -> buf1
        __syncthreads();
        gl2lds16(kg, &Ks[1][tid << 3]);
        gl2lds16(vg, &Vt[1][tid << 3]);
        kg += 4096; vg += 64;
        #pragma unroll
        for (int reg = 0; reg < 4; ++reg)
            mB[reg] = *(const float4*)(mptr + (reg << 11));
        mptr += 64;

        FLASH_STEP(0, mA)

        // ---- half B: compute kt=2it+1 (buf1, mB); stage kt=2it+2 -> buf0
        __syncthreads();
        if (it < 15) {
            gl2lds16(kg, &Ks[0][tid << 3]);
            gl2lds16(vg, &Vt[0][tid << 3]);
            kg += 4096; vg += 64;
            #pragma unroll
            for (int reg = 0; reg < 4; ++reg)
                mA[reg] = *(const float4*)(mptr + (reg << 11));
            mptr += 64;
        }

        FLASH_STEP(1, mB)
    }
#undef FLASH_STEP

    #pragma unroll
    for (int reg = 0; reg < 4; ++reg) {
        float l = l_i[reg];
        l += __shfl_xor(l, 1);
        l += __shfl_xor(l, 2);
        l += __shfl_xor(l, 4);
        l += __shfl_xor(l, 8);
        const float inv = 1.0f / l;
        const int qr = q0 + (wave << 4) + (quad << 2) + reg;
        unsigned short* op = attn + (((size_t)((b_ << 11) + qr)) << 10) + (h << 6);
        #pragma unroll
        for (int j = 0; j < 4; ++j)
            op[(j << 4) + ln] = f2bf(O[j][reg] * inv);
    }
}

// =====================================================================
// Kernel 4: out = attn @ Wo^T + bo, bf16 MFMA, fp32 out.
// tau-permuted Wo row staging -> lane's 4 columns contiguous -> float4
// stores + float4 bias. Output layout identity.
// =====================================================================
__global__ __launch_bounds__(256, 3) void out_gemm_kernel(
    const unsigned short* __restrict__ X, const unsigned short* __restrict__ W,
    const float* __restrict__ bias, float* __restrict__ out)
{
    __shared__ unsigned short As[128 * 64];
    __shared__ unsigned short Bs[128 * 64];

    const int n0 = blockIdx.x << 7;
    const int m0 = blockIdx.y << 7;
    const int tid = threadIdx.x;
    const int wave = tid >> 6, lane = tid & 63;
    const int quad = lane >> 4, ln = lane & 15;
    const int wm = (wave >> 1) << 6, wn = (wave & 1) << 6;

    const unsigned short* xptr[4];
    const unsigned short* wptr[4];
    #pragma unroll
    for (int L = 0; L < 4; ++L) {
        const int i = tid + (L << 8);
        const int r = i >> 3, cl = i & 7;
        const int cg = (cl ^ (r & 7)) << 3;
        const int rq = r & 63;
        const int tau = (r & 64) | ((rq & 15) << 2) | (rq >> 4);
        xptr[L] = X + (m0 + r) * 1024 + cg;
        wptr[L] = W + (n0 + tau) * 1024 + cg;
    }

    f32x4 acc[4][4] = {};

    for (int k0 = 0; k0 < 1024; k0 += 64) {
        #pragma unroll
        for (int L = 0; L < 4; ++L) {
            const int i = tid + (L << 8);
            gl2lds16(xptr[L] + k0, &As[i << 3]);
            gl2lds16(wptr[L] + k0, &Bs[i << 3]);
        }
        __syncthreads();
        #pragma unroll
        for (int s = 0; s < 2; ++s) {
            bf16x8 a[4], b[4];
            #pragma unroll
            for (int t = 0; t < 4; ++t) {
                const int ra = wm + (t << 4) + ln;
                a[t] = *(const bf16x8*)&As[(ra << 6) + ((((s << 2) | quad) ^ (ra & 7)) << 3)];
                const int rb = wn + (t << 4) + ln;
                b[t] = *(const bf16x8*)&Bs[(rb << 6) + ((((s << 2) | quad) ^ (rb & 7)) << 3)];
            }
            #pragma unroll
            for (int i = 0; i < 4; ++i)
                #pragma unroll
                for (int j = 0; j < 4; ++j)
                    acc[i][j] = __builtin_amdgcn_mfma_f32_16x16x32_bf16(a[i], b[j], acc[i][j], 0, 0, 0);
        }
        __syncthreads();
    }

    const float4 bv4 = *(const float4*)(bias + n0 + wn + (ln << 2));

    #pragma unroll
    for (int i = 0; i < 4; ++i)
        #pragma unroll
        for (int reg = 0; reg < 4; ++reg) {
            const int m = m0 + wm + (i << 4) + (quad << 2) + reg;
            float4 ov;
            ov.x = acc[i][0][reg] + bv4.x;
            ov.y = acc[i][1][reg] + bv4.y;
            ov.z = acc[i][2][reg] + bv4.z;
            ov.w = acc[i][3][reg] + bv4.w;
            *(float4*)(out + m * 1024 + n0 + wn + (ln << 2)) = ov;
        }
}

// =====================================================================
extern "C" void kernel_launch(void* const* d_in, const int* in_sizes, int n_in,
                              void* d_out, int out_size, void* d_ws, size_t ws_size,
                              hipStream_t stream)
{
    const float* hs   = (const float*)d_in[0];
    const float* mask = (const float*)d_in[1];
    const float* Wq   = (const float*)d_in[2];
    const float* bq   = (const float*)d_in[3];
    const float* Wk   = (const float*)d_in[4];
    const float* bk   = (const float*)d_in[5];
    const float* Wv   = (const float*)d_in[6];
    const float* bv   = (const float*)d_in[7];
    const float* Wo   = (const float*)d_in[8];
    const float* bo   = (const float*)d_in[9];

    unsigned short* ws = (unsigned short*)d_ws;
    const size_t M1 = (size_t)1 << 20;
    unsigned short* hsb   = ws;              // 4M
    unsigned short* wall  = ws + 4 * M1;     // wq|wk|wv
    unsigned short* wob   = ws + 7 * M1;
    unsigned short* qbf   = ws + 8 * M1;
    unsigned short* kbf   = ws + 12 * M1;
    unsigned short* vbf   = ws + 16 * M1;
    unsigned short* vtb   = ws + 20 * M1;
    unsigned short* attnb = ws + 24 * M1;
    float2*         rtab  = (float2*)(ws + 28 * M1);   // 512KB

    convert_kernel<<<8448, 256, 0, stream>>>(hs, Wq, Wk, Wv, Wo, ws, rtab);
    qkv_gemm_kernel<<<dim3(24, 32), 256, 0, stream>>>(hsb, wall, bq, bk, bv, rtab, qbf, kbf, vbf);
    vtrans_kernel<<<1024, 256, 0, stream>>>(vbf, vtb);
    flash_kernel<<<512, 512, 0, stream>>>(qbf, kbf, vtb, mask, attnb);
    out_gemm_kernel<<<dim3(8, 32), 256, 0, stream>>>(attnb, wob, bo, (float*)d_out);
}

// Round 4
// 220.891 us; speedup vs baseline: 1.0415x; 1.0415x over previous
//
#include <hip/hip_runtime.h>
#include <math.h>

#define S_LEN 2048
#define NHEAD 16
#define HDIM  64

typedef __attribute__((ext_vector_type(8))) short bf16x8;
typedef __attribute__((ext_vector_type(4))) float f32x4;

__device__ __forceinline__ unsigned short f2bf(float f) {
    union { float f; unsigned u; } v; v.f = f;
    unsigned r = v.u + 0x7fffu + ((v.u >> 16) & 1u);
    return (unsigned short)(r >> 16);
}

// async 16B global->LDS. LDS dest must be wave-uniform base + lane*16.
__device__ __forceinline__ void gl2lds16(const void* g, void* l) {
    __builtin_amdgcn_global_load_lds(
        (__attribute__((address_space(1))) void*)(void*)(g),
        (__attribute__((address_space(3))) void*)(l), 16, 0, 0);
}

// =====================================================================
// Kernel 0: fused fp32->bf16 convert (blocks 0..8191) + RoPE table build
// (blocks 8192..8447). dst: hs[4M] | Wq[1M] | Wk[1M] | Wv[1M] | Wo[1M]
// =====================================================================
__global__ __launch_bounds__(256) void convert_kernel(
    const float* __restrict__ hs, const float* __restrict__ Wq,
    const float* __restrict__ Wk, const float* __restrict__ Wv,
    const float* __restrict__ Wo, unsigned short* __restrict__ dst,
    float2* __restrict__ rtab)
{
    const int bid = blockIdx.x;
    if (bid >= 8192) {
        const int gid = (bid - 8192) * 256 + threadIdx.x;   // 65536
        const int s = gid >> 5, i = gid & 31;
        const float l2c = 0.41524101186092029f;             // log2(10000)/32
        const float freq = exp2f(-(float)i * l2c);
        const float ang = (float)s * freq;
        float2 cs;
        cs.x = cosf(ang);
        cs.y = sinf(ang);
        rtab[gid] = cs;
        return;
    }
    const int gid = bid * 256 + threadIdx.x;
    const int n = gid << 2;
    const float* src; int off;
    if (n < (4 << 20))      { src = hs; off = n; }
    else if (n < (5 << 20)) { src = Wq; off = n - (4 << 20); }
    else if (n < (6 << 20)) { src = Wk; off = n - (5 << 20); }
    else if (n < (7 << 20)) { src = Wv; off = n - (6 << 20); }
    else                    { src = Wo; off = n - (7 << 20); }
    const float4 v = *(const float4*)(src + off);
    ushort4 o;
    o.x = f2bf(v.x); o.y = f2bf(v.y); o.z = f2bf(v.z); o.w = f2bf(v.w);
    *(ushort4*)(dst + n) = o;
}

// =====================================================================
// Kernel 1: QKV GEMM, bf16 MFMA 16x16x32, tile 128x128 BK=64, RoPE fused.
// B-rows staged PERMUTED (tau) so each lane's 4 output columns pack:
//   Q/K: tau(r) = 2*ln + (jt&1) + 32*(jt>>1)  -> lane holds {n,n+1,n+32,n+33}
//        RoPE pairs in-lane, 1 float4 rtab load, 2x b32 stores
//   V:   tau(r) = 4*ln + jt                   -> 1x b64 store, float4 bias
// Output layouts stay IDENTITY -> zero downstream changes.
// =====================================================================
__global__ __launch_bounds__(256, 3) void qkv_gemm_kernel(
    const unsigned short* __restrict__ X,     // [4096][1024] bf16
    const unsigned short* __restrict__ Wall,  // wq|wk|wv (1M each)
    const float* __restrict__ bq, const float* __restrict__ bk,
    const float* __restrict__ bv, const float2* __restrict__ rtab,
    unsigned short* __restrict__ qo, unsigned short* __restrict__ ko,
    unsigned short* __restrict__ vo)
{
    __shared__ unsigned short As[128 * 64];
    __shared__ unsigned short Bs[128 * 64];

    const int mat = blockIdx.x >> 3;
    const int n0  = (blockIdx.x & 7) << 7;
    const int m0  = blockIdx.y << 7;
    const unsigned short* W = Wall + (mat << 20);
    const float* bias = (mat == 0) ? bq : (mat == 1) ? bk : bv;
    unsigned short* out = (mat == 0) ? qo : (mat == 1) ? ko : vo;

    const int tid = threadIdx.x;
    const int wave = tid >> 6, lane = tid & 63;
    const int quad = lane >> 4, ln = lane & 15;
    const int wm = (wave >> 1) << 6, wn = (wave & 1) << 6;

    // hoisted staging pointers (tau row-permutation on B)
    const unsigned short* xptr[4];
    const unsigned short* wptr[4];
    #pragma unroll
    for (int L = 0; L < 4; ++L) {
        const int i = tid + (L << 8);
        const int r = i >> 3, cl = i & 7;
        const int cg = (cl ^ (r & 7)) << 3;
        const int rq = r & 63;
        const int tau = (mat < 2)
            ? ((r & 64) | ((rq & 15) << 1) | ((rq >> 4) & 1) | (((rq >> 5) & 1) << 5))
            : ((r & 64) | ((rq & 15) << 2) | (rq >> 4));
        xptr[L] = X + (m0 + r) * 1024 + cg;
        wptr[L] = W + (n0 + tau) * 1024 + cg;
    }

    f32x4 acc[4][4] = {};

    for (int k0 = 0; k0 < 1024; k0 += 64) {
        #pragma unroll
        for (int L = 0; L < 4; ++L) {
            const int i = tid + (L << 8);
            gl2lds16(xptr[L] + k0, &As[i << 3]);
            gl2lds16(wptr[L] + k0, &Bs[i << 3]);
        }
        __syncthreads();
        #pragma unroll
        for (int s = 0; s < 2; ++s) {
            bf16x8 a[4], b[4];
            #pragma unroll
            for (int t = 0; t < 4; ++t) {
                const int ra = wm + (t << 4) + ln;
                a[t] = *(const bf16x8*)&As[(ra << 6) + ((((s << 2) | quad) ^ (ra & 7)) << 3)];
                const int rb = wn + (t << 4) + ln;
                b[t] = *(const bf16x8*)&Bs[(rb << 6) + ((((s << 2) | quad) ^ (rb & 7)) << 3)];
            }
            #pragma unroll
            for (int i = 0; i < 4; ++i)
                #pragma unroll
                for (int j = 0; j < 4; ++j)
                    acc[i][j] = __builtin_amdgcn_mfma_f32_16x16x32_bf16(a[i], b[j], acc[i][j], 0, 0, 0);
        }
        __syncthreads();
    }

    const int h = (n0 + wn) >> 6;

    if (mat < 2) {
        const int nb = n0 + wn + (ln << 1);
        const float b0 = bias[nb],      b1 = bias[nb + 1];
        const float b2 = bias[nb + 32], b3 = bias[nb + 33];
        #pragma unroll
        for (int i = 0; i < 4; ++i) {
            #pragma unroll
            for (int reg = 0; reg < 4; ++reg) {
                const int m = m0 + wm + (i << 4) + (quad << 2) + reg;
                const int b_ = m >> 11, s_ = m & 2047;
                unsigned short* o = out + ((((b_ << 4) + h) << 11) + s_) * 64;
                const float4 cs = *(const float4*)(rtab + (s_ << 5) + (ln << 1));
                const float x1a = acc[i][0][reg] + b0, x1b = acc[i][1][reg] + b1;
                const float x2a = acc[i][2][reg] + b2, x2b = acc[i][3][reg] + b3;
                const float r0a = x1a * cs.x - x2a * cs.y;
                const float r0b = x1b * cs.z - x2b * cs.w;
                const float r1a = x2a * cs.x + x1a * cs.y;
                const float r1b = x2b * cs.z + x1b * cs.w;
                const unsigned ua = __float_as_uint(r0a) + 0x8000u;
                const unsigned ub = __float_as_uint(r0b) + 0x8000u;
                const unsigned uc = __float_as_uint(r1a) + 0x8000u;
                const unsigned ud = __float_as_uint(r1b) + 0x8000u;
                *(unsigned*)(o + (ln << 1))      = __builtin_amdgcn_perm(ub, ua, 0x07060302u);
                *(unsigned*)(o + 32 + (ln << 1)) = __builtin_amdgcn_perm(ud, uc, 0x07060302u);
            }
        }
    } else {
        const float4 bv4 = *(const float4*)(bias + n0 + wn + (ln << 2));
        #pragma unroll
        for (int i = 0; i < 4; ++i)
            #pragma unroll
            for (int reg = 0; reg < 4; ++reg) {
                const int m = m0 + wm + (i << 4) + (quad << 2) + reg;
                const int b_ = m >> 11, s_ = m & 2047;
                unsigned short* o = out + ((((b_ << 4) + h) << 11) + s_) * 64;
                const unsigned ua = __float_as_uint(acc[i][0][reg] + bv4.x) + 0x8000u;
                const unsigned ub = __float_as_uint(acc[i][1][reg] + bv4.y) + 0x8000u;
                const unsigned uc = __float_as_uint(acc[i][2][reg] + bv4.z) + 0x8000u;
                const unsigned ud = __float_as_uint(acc[i][3][reg] + bv4.w) + 0x8000u;
                uint2 w;
                w.x = __builtin_amdgcn_perm(ub, ua, 0x07060302u);
                w.y = __builtin_amdgcn_perm(ud, uc, 0x07060302u);
                *(uint2*)(o + (ln << 2)) = w;
            }
    }
}

// =====================================================================
// Kernel 2: V transpose [B,H,S,HD] -> [B,H,HD,S] (identity layouts).
// =====================================================================
__global__ __launch_bounds__(256) void vtrans_kernel(
    const unsigned short* __restrict__ v, unsigned short* __restrict__ vt)
{
    __shared__ unsigned short T[64][66];
    const int bh = blockIdx.x >> 5;
    const int s0 = (blockIdx.x & 31) << 6;
    const int tid = threadIdx.x;
    #pragma unroll
    for (int L = 0; L < 4; ++L) {
        const int i = tid + (L << 8);
        const int r = i >> 4, c4 = (i & 15) << 2;
        const ushort4 in = *(const ushort4*)(v + ((bh << 11) + s0 + r) * 64 + c4);
        T[r][c4 + 0] = in.x; T[r][c4 + 1] = in.y;
        T[r][c4 + 2] = in.z; T[r][c4 + 3] = in.w;
    }
    __syncthreads();
    #pragma unroll
    for (int L = 0; L < 4; ++L) {
        const int i = tid + (L << 8);
        const int hd = i >> 4, c4 = (i & 15) << 2;
        ushort4 o;
        o.x = T[c4 + 0][hd]; o.y = T[c4 + 1][hd];
        o.z = T[c4 + 2][hd]; o.w = T[c4 + 3][hd];
        *(ushort4*)(vt + ((bh << 6) + hd) * 2048 + s0 + c4) = o;
    }
}

// =====================================================================
// Kernel 3: flash v9 — v8 + counted-vmcnt barriers (T4).
// __syncthreads() drains vmcnt(0): it serialized the 4 HBM mask loads
// (~900cy latency) onto every barrier, 2x per kt. Replace with raw
// s_barrier + s_waitcnt vmcnt(4): waits ONLY the 2 gl2lds staging loads
// (pinned oldest via an empty memory-clobber asm between gl2lds pair and
// mask loads); mask loads stay in flight across the barrier and are
// waited by the compiler at first use (mid-softmax, ~1 half-kt later).
// Safety: Ps is per-wave (no cross-wave lgkm dep -> dropping lgkm drain
// is sound); Ks/Vt cross-wave visibility is vmcnt-domain, covered.
// =====================================================================
__global__ __launch_bounds__(512, 4) void flash_kernel(
    const unsigned short* __restrict__ qb, const unsigned short* __restrict__ kb,
    const unsigned short* __restrict__ vtb, const float* __restrict__ mask,
    unsigned short* __restrict__ attn)
{
    __shared__ unsigned short Ks[2][64 * 64];
    __shared__ unsigned short Vt[2][64 * 64];
    __shared__ unsigned short Ps[8 * 1024];

    const int qt = blockIdx.x & 15;
    const int bh = blockIdx.x >> 4;
    const int b_ = bh >> 4, h = bh & 15;
    const int q0 = qt << 7;

    const int tid = threadIdx.x;
    const int wave = tid >> 6, lane = tid & 63;
    const int quad = lane >> 4, ln = lane & 15;

    const unsigned short* qrow = qb + ((size_t)((bh << 11) + q0 + (wave << 4) + ln) << 6);
    bf16x8 qa0 = *(const bf16x8*)(qrow + (quad << 3));
    bf16x8 qa1 = *(const bf16x8*)(qrow + 32 + (quad << 3));

    const float scale = 0.125f / logf(2048.0f);

    unsigned short* Pw = Ps + (wave << 10);

    // ---- hoisted swizzled LDS offsets (loop-invariant) ----
    int kvo0[4], kvo1[4];
    #pragma unroll
    for (int j = 0; j < 4; ++j) {
        const int r = (j << 4) + ln;
        kvo0[j] = (r << 6) + ((quad ^ (r & 7)) << 3);
        kvo1[j] = kvo0[j] ^ 32;
    }
    int po[4];
    #pragma unroll
    for (int reg = 0; reg < 4; ++reg) {
        const int pr = (quad << 2) + reg;
        po[reg] = (pr << 6) + (((ln >> 1) ^ (pr & 7)) << 3) + ((ln & 1) << 2);
    }
    const int pro0 = (ln << 6) + ((quad ^ (ln & 7)) << 3);
    const int pro1 = pro0 ^ 32;

    // ---- running global pointers ----
    const int r0 = tid >> 3, c0 = ((tid & 7) ^ (r0 & 7)) << 3;
    const int p0 = ((r0 & 15) << 2) + (r0 >> 4);
    const unsigned short* kg = kb + ((bh << 11) + p0) * 64 + c0;
    const unsigned short* vg = vtb + ((bh << 6) + r0) * 2048 + c0;
    const float* mptr = mask + ((size_t)b_ << 22)
                      + ((size_t)(q0 + (wave << 4) + (quad << 2)) << 11) + (ln << 2);

    float l_i[4] = {0.f, 0.f, 0.f, 0.f};
    f32x4 O[4] = {};

// counted-vmcnt barrier: wait only the 2 staging gl2lds (oldest of <=6
// outstanding); mask loads stay in flight across the barrier.
#define FLASH_SYNC()                                              \
    do {                                                          \
        asm volatile("s_waitcnt vmcnt(4)" ::: "memory");          \
        __builtin_amdgcn_s_barrier();                             \
    } while (0)
#define VMEM_PIN() asm volatile("" ::: "memory")

    // prologue: stage kt0 -> buf0, load mask kt0 -> mA
    gl2lds16(kg, &Ks[0][tid << 3]);
    gl2lds16(vg, &Vt[0][tid << 3]);
    VMEM_PIN();
    kg += 4096; vg += 64;
    float4 mA[4], mB[4];
    #pragma unroll
    for (int reg = 0; reg < 4; ++reg)
        mA[reg] = *(const float4*)(mptr + (reg << 11));
    mptr += 64;

#define FLASH_STEP(BUF, MR)                                                   \
    {                                                                         \
        f32x4 sacc[4] = {};                                                   \
        {                                                                     \
            bf16x8 bfr[4];                                                    \
            _Pragma("unroll")                                                 \
            for (int j = 0; j < 4; ++j)                                       \
                bfr[j] = *(const bf16x8*)&Ks[BUF][kvo0[j]];                   \
            __builtin_amdgcn_s_setprio(1);                                    \
            _Pragma("unroll")                                                 \
            for (int j = 0; j < 4; ++j)                                       \
                sacc[j] = __builtin_amdgcn_mfma_f32_16x16x32_bf16(            \
                    qa0, bfr[j], sacc[j], 0, 0, 0);                           \
            __builtin_amdgcn_s_setprio(0);                                    \
            _Pragma("unroll")                                                 \
            for (int j = 0; j < 4; ++j)                                       \
                bfr[j] = *(const bf16x8*)&Ks[BUF][kvo1[j]];                   \
            __builtin_amdgcn_s_setprio(1);                                    \
            _Pragma("unroll")                                                 \
            for (int j = 0; j < 4; ++j)                                       \
                sacc[j] = __builtin_amdgcn_mfma_f32_16x16x32_bf16(            \
                    qa1, bfr[j], sacc[j], 0, 0, 0);                           \
            __builtin_amdgcn_s_setprio(0);                                    \
        }                                                                     \
        _Pragma("unroll")                                                     \
        for (int reg = 0; reg < 4; ++reg) {                                   \
            float p0_ = __expf(fmaf(sacc[0][reg], scale, MR[reg].x));         \
            float p1_ = __expf(fmaf(sacc[1][reg], scale, MR[reg].y));         \
            float p2_ = __expf(fmaf(sacc[2][reg], scale, MR[reg].z));         \
            float p3_ = __expf(fmaf(sacc[3][reg], scale, MR[reg].w));         \
            l_i[reg] += (p0_ + p1_) + (p2_ + p3_);                            \
            unsigned u0 = __float_as_uint(p0_) + 0x8000u;                     \
            unsigned u1 = __float_as_uint(p1_) + 0x8000u;                     \
            unsigned u2 = __float_as_uint(p2_) + 0x8000u;                     \
            unsigned u3 = __float_as_uint(p3_) + 0x8000u;                     \
            uint2 w;                                                          \
            w.x = __builtin_amdgcn_perm(u1, u0, 0x07060302u);                 \
            w.y = __builtin_amdgcn_perm(u3, u2, 0x07060302u);                 \
            *(uint2*)&Pw[po[reg]] = w;                                        \
        }                                                                     \
        {                                                                     \
            bf16x8 a_ = *(const bf16x8*)&Pw[pro0];                            \
            bf16x8 bfr[4];                                                    \
            _Pragma("unroll")                                                 \
            for (int j = 0; j < 4; ++j)                                       \
                bfr[j] = *(const bf16x8*)&Vt[BUF][kvo0[j]];                   \
            __builtin_amdgcn_s_setprio(1);                                    \
            _Pragma("unroll")                                                 \
            for (int j = 0; j < 4; ++j)                                       \
                O[j] = __builtin_amdgcn_mfma_f32_16x16x32_bf16(               \
                    a_, bfr[j], O[j], 0, 0, 0);                               \
            __builtin_amdgcn_s_setprio(0);                                    \
            a_ = *(const bf16x8*)&Pw[pro1];                                   \
            _Pragma("unroll")                                                 \
            for (int j = 0; j < 4; ++j)                                       \
                bfr[j] = *(const bf16x8*)&Vt[BUF][kvo1[j]];                   \
            __builtin_amdgcn_s_setprio(1);                                    \
            _Pragma("unroll")                                                 \
            for (int j = 0; j < 4; ++j)                                       \
                O[j] = __builtin_amdgcn_mfma_f32_16x16x32_bf16(               \
                    a_, bfr[j], O[j], 0, 0, 0);                               \
            __builtin_amdgcn_s_setprio(0);                                    \
        }                                                                     \
    }

    for (int it = 0; it < 16; ++it) {
        // ---- half A: compute kt=2it (buf0, mA); stage kt=2it+1 -> buf1
        FLASH_SYNC();
        gl2lds16(kg, &Ks[1][tid << 3]);
        gl2lds16(vg, &Vt[1][tid << 3]);
        VMEM_PIN();
        kg += 4096; vg += 64;
        #pragma unroll
        for (int reg = 0; reg < 4; ++reg)
            mB[reg] = *(const float4*)(mptr + (reg << 11));
        mptr += 64;

        FLASH_STEP(0, mA)

        // ---- half B: compute kt=2it+1 (buf1, mB); stage kt=2it+2 -> buf0
        FLASH_SYNC();
        if (it < 15) {
            gl2lds16(kg, &Ks[0][tid << 3]);
            gl2lds16(vg, &Vt[0][tid << 3]);
            VMEM_PIN();
            kg += 4096; vg += 64;
            #pragma unroll
            for (int reg = 0; reg < 4; ++reg)
                mA[reg] = *(const float4*)(mptr + (reg << 11));
            mptr += 64;
        }

        FLASH_STEP(1, mB)
    }
#undef FLASH_STEP
#undef FLASH_SYNC
#undef VMEM_PIN

    #pragma unroll
    for (int reg = 0; reg < 4; ++reg) {
        float l = l_i[reg];
        l += __shfl_xor(l, 1);
        l += __shfl_xor(l, 2);
        l += __shfl_xor(l, 4);
        l += __shfl_xor(l, 8);
        const float inv = 1.0f / l;
        const int qr = q0 + (wave << 4) + (quad << 2) + reg;
        unsigned short* op = attn + (((size_t)((b_ << 11) + qr)) << 10) + (h << 6);
        #pragma unroll
        for (int j = 0; j < 4; ++j)
            op[(j << 4) + ln] = f2bf(O[j][reg] * inv);
    }
}

// =====================================================================
// Kernel 4: out = attn @ Wo^T + bo, bf16 MFMA, fp32 out.
// tau-permuted Wo row staging -> lane's 4 columns contiguous -> float4
// stores + float4 bias. Output layout identity.
// =====================================================================
__global__ __launch_bounds__(256, 3) void out_gemm_kernel(
    const unsigned short* __restrict__ X, const unsigned short* __restrict__ W,
    const float* __restrict__ bias, float* __restrict__ out)
{
    __shared__ unsigned short As[128 * 64];
    __shared__ unsigned short Bs[128 * 64];

    const int n0 = blockIdx.x << 7;
    const int m0 = blockIdx.y << 7;
    const int tid = threadIdx.x;
    const int wave = tid >> 6, lane = tid & 63;
    const int quad = lane >> 4, ln = lane & 15;
    const int wm = (wave >> 1) << 6, wn = (wave & 1) << 6;

    const unsigned short* xptr[4];
    const unsigned short* wptr[4];
    #pragma unroll
    for (int L = 0; L < 4; ++L) {
        const int i = tid + (L << 8);
        const int r = i >> 3, cl = i & 7;
        const int cg = (cl ^ (r & 7)) << 3;
        const int rq = r & 63;
        const int tau = (r & 64) | ((rq & 15) << 2) | (rq >> 4);
        xptr[L] = X + (m0 + r) * 1024 + cg;
        wptr[L] = W + (n0 + tau) * 1024 + cg;
    }

    f32x4 acc[4][4] = {};

    for (int k0 = 0; k0 < 1024; k0 += 64) {
        #pragma unroll
        for (int L = 0; L < 4; ++L) {
            const int i = tid + (L << 8);
            gl2lds16(xptr[L] + k0, &As[i << 3]);
            gl2lds16(wptr[L] + k0, &Bs[i << 3]);
        }
        __syncthreads();
        #pragma unroll
        for (int s = 0; s < 2; ++s) {
            bf16x8 a[4], b[4];
            #pragma unroll
            for (int t = 0; t < 4; ++t) {
                const int ra = wm + (t << 4) + ln;
                a[t] = *(const bf16x8*)&As[(ra << 6) + ((((s << 2) | quad) ^ (ra & 7)) << 3)];
                const int rb = wn + (t << 4) + ln;
                b[t] = *(const bf16x8*)&Bs[(rb << 6) + ((((s << 2) | quad) ^ (rb & 7)) << 3)];
            }
            #pragma unroll
            for (int i = 0; i < 4; ++i)
                #pragma unroll
                for (int j = 0; j < 4; ++j)
                    acc[i][j] = __builtin_amdgcn_mfma_f32_16x16x32_bf16(a[i], b[j], acc[i][j], 0, 0, 0);
        }
        __syncthreads();
    }

    const float4 bv4 = *(const float4*)(bias + n0 + wn + (ln << 2));

    #pragma unroll
    for (int i = 0; i < 4; ++i)
        #pragma unroll
        for (int reg = 0; reg < 4; ++reg) {
            const int m = m0 + wm + (i << 4) + (quad << 2) + reg;
            float4 ov;
            ov.x = acc[i][0][reg] + bv4.x;
            ov.y = acc[i][1][reg] + bv4.y;
            ov.z = acc[i][2][reg] + bv4.z;
            ov.w = acc[i][3][reg] + bv4.w;
            *(float4*)(out + m * 1024 + n0 + wn + (ln << 2)) = ov;
        }
}

// =====================================================================
extern "C" void kernel_launch(void* const* d_in, const int* in_sizes, int n_in,
                              void* d_out, int out_size, void* d_ws, size_t ws_size,
                              hipStream_t stream)
{
    const float* hs   = (const float*)d_in[0];
    const float* mask = (const float*)d_in[1];
    const float* Wq   = (const float*)d_in[2];
    const float* bq   = (const float*)d_in[3];
    const float* Wk   = (const float*)d_in[4];
    const float* bk   = (const float*)d_in[5];
    const float* Wv   = (const float*)d_in[6];
    const float* bv   = (const float*)d_in[7];
    const float* Wo   = (const float*)d_in[8];
    const float* bo   = (const float*)d_in[9];

    unsigned short* ws = (unsigned short*)d_ws;
    const size_t M1 = (size_t)1 << 20;
    unsigned short* hsb   = ws;              // 4M
    unsigned short* wall  = ws + 4 * M1;     // wq|wk|wv
    unsigned short* wob   = ws + 7 * M1;
    unsigned short* qbf   = ws + 8 * M1;
    unsigned short* kbf   = ws + 12 * M1;
    unsigned short* vbf   = ws + 16 * M1;
    unsigned short* vtb   = ws + 20 * M1;
    unsigned short* attnb = ws + 24 * M1;
    float2*         rtab  = (float2*)(ws + 28 * M1);   // 512KB

    convert_kernel<<<8448, 256, 0, stream>>>(hs, Wq, Wk, Wv, Wo, ws, rtab);
    qkv_gemm_kernel<<<dim3(24, 32), 256, 0, stream>>>(hsb, wall, bq, bk, bv, rtab, qbf, kbf, vbf);
    vtrans_kernel<<<1024, 256, 0, stream>>>(vbf, vtb);
    flash_kernel<<<512, 512, 0, stream>>>(qbf, kbf, vtb, mask, attnb);
    out_gemm_kernel<<<dim3(8, 32), 256, 0, stream>>>(attnb, wob, bo, (float*)d_out);
}